// Round 1
// 408.355 us; speedup vs baseline: 1.0026x; 1.0026x over previous
//
#include <hip/hip_runtime.h>

typedef __attribute__((ext_vector_type(8))) short short8;
typedef __attribute__((ext_vector_type(4))) float f32x4;

#define NN 8192
#define DD 64

// f32 -> bf16 RNE (y staging + part staging)
__device__ inline unsigned short f2bf(float f){
  unsigned b = __float_as_uint(f);
  b = (b + 0x7fffu + ((b >> 16) & 1u)) >> 16;
  return (unsigned short)b;
}

// async global->LDS, 16B per lane; LDS dest = uniform base + lane*16
__device__ __forceinline__ void glds16(const void* g, void* l){
  __builtin_amdgcn_global_load_lds((const __attribute__((address_space(1))) void*)g,
                                   (__attribute__((address_space(3))) void*)l, 16, 0, 0);
}

// ---------------------------------------------------------------------------
// Algebra (verified in prior session): softmax rows sum to 1 -> attn_agg ==
// aggregated; Wa_* unused.
//   out = x@(Wobj+Wskip) + r@Wrel + A^T @ (x@Wnobj + bnobj) + (bobj+brel+bskip)
// A is exactly 0/1 -> f32 truncation to hi-ushort IS the exact bf16.
//
// R8: (1) part f32->bf16, KSPLIT 16->8 (part round-trip 64->16 MB);
//     (2) A staged via global_load_lds as raw f32 (no reg round-trip, no
//         repack, no ds_write) with source-XOR chunk swizzle; B-frags read
//         the hi-ushort of each f32 directly (exact);
//     (3) k_proj re-read 16x->8x; k_out rebuilt for bf16 part.
// ---------------------------------------------------------------------------

// Kernel 1: accT[d][i] = x@(Wobj+Wskip)+r@Wrel+biases ; yT[d][i]=bf16(x@Wnobj+bnobj)
__global__ __launch_bounds__(256) void k_proj(
    const float* __restrict__ x, const float* __restrict__ r,
    const float* __restrict__ Wobj,  const float* __restrict__ bobj,
    const float* __restrict__ Wnobj, const float* __restrict__ bnobj,
    const float* __restrict__ Wrel,  const float* __restrict__ brel,
    const float* __restrict__ Wskip, const float* __restrict__ bskip,
    float* __restrict__ accT, unsigned short* __restrict__ yT)
{
  const int i  = blockIdx.x * 256 + threadIdx.x;   // row
  const int d0 = blockIdx.y * 8;                   // 8 output dims

  float ay[8], az[8];
#pragma unroll
  for (int t = 0; t < 8; t++){ ay[t] = 0.f; az[t] = 0.f; }

  const float4* xp = (const float4*)(x + (size_t)i * DD);
  const float4* rp = (const float4*)(r + (size_t)i * DD);

#pragma unroll
  for (int kb = 0; kb < 4; kb++){                  // 16 k per chunk
    float xv[16], rv[16];
#pragma unroll
    for (int p = 0; p < 4; p++){
      float4 u = xp[kb*4 + p];
      xv[4*p+0]=u.x; xv[4*p+1]=u.y; xv[4*p+2]=u.z; xv[4*p+3]=u.w;
      float4 v = rp[kb*4 + p];
      rv[4*p+0]=v.x; rv[4*p+1]=v.y; rv[4*p+2]=v.z; rv[4*p+3]=v.w;
    }
#pragma unroll
    for (int kk = 0; kk < 16; kk++){
      const int wb = (kb*16 + kk) * DD + d0;       // uniform -> s_loads
      const float xk = xv[kk], rk = rv[kk];
#pragma unroll
      for (int t = 0; t < 8; t++){
        ay[t] += xk * Wnobj[wb + t];
        az[t] += xk * Wobj [wb + t];
        az[t] += xk * Wskip[wb + t];
        az[t] += rk * Wrel [wb + t];
      }
    }
  }

#pragma unroll
  for (int t = 0; t < 8; t++){
    ay[t] += bnobj[d0 + t];
    az[t] += bobj[d0 + t] + brel[d0 + t] + bskip[d0 + t];
    yT[(size_t)(d0 + t) * NN + i]   = f2bf(ay[t]);   // coalesced
    accT[(size_t)(d0 + t) * NN + i] = az[t];
  }
}

// ---------------------------------------------------------------------------
// Kernel 2: partb[kb][d][j] = bf16( sum_{k in chunk} yT[d][k]*A[k][j] )
// BN=128, KSPLIT=8 -> grid 512 blocks = 2/CU. A tile 32k x 128j staged as
// RAW f32 by global_load_lds (16 KB/tile, double-buffered = 32 KB) + y tile
// 5 KB x2 -> 42 KB LDS. B-frag = hi-ushort of each f32 (exact bf16 of 0/1).
//
// Swizzle invariant: staging wave w owns rows w*8..w*8+7; lane writes LDS
// chunk (lane&31) from global chunk (lane&31)^(4w). Read of row k (k>>3==q)
// fetches global chunk g at LDS chunk g^(4q) -> keys match. Per-instr banks:
// 4 q-groups in 4 distinct 64B regions of 256B -> 2-way (free, m136).
// ---------------------------------------------------------------------------
#define BN 128
#define KSPLIT 8
#define KCH (NN / KSPLIT)    // 1024
#define KT 32                // k-depth per tile (one MFMA K)
#define NIT (KCH / KT)       // 32
#define ATILE (KT * BN)      // 4096 floats = 16 KB
#define YPITCH 40            // 32 + 8: af ds_read_b128 stays 2-way
#define YSZ (DD * YPITCH)    // 2560 shorts = 5 KB

__global__ __launch_bounds__(256) void k_spmm(
    const float* __restrict__ A,
    const unsigned short* __restrict__ yT,
    unsigned short* __restrict__ partb)
{
  __shared__ float Af[2 * ATILE];     // 32 KB
  __shared__ short Ylds[2 * YSZ];     // 10 KB

  const int tid  = threadIdx.x;
  const int lane = tid & 63;
  const int wave = tid >> 6;
  const int q    = lane >> 4;    // k-quad within fragment
  const int nn   = lane & 15;    // m (A-frag) / n (B-frag, C col) index

  const int j0     = blockIdx.x * BN;
  const int kstart = blockIdx.y * KCH;

  // y staging: 64 d-rows x 4 8-k chunks (reg path; tiny)
  const int cY = tid & 3;
  const int m  = tid >> 2;       // 0..63
  const unsigned short* yp = yT + (size_t)m * NN + kstart + cY * 8;

  // A DMA: wave w, call p: rows k0=w*8+2p, k0+1 (512 B each = half-wave)
  const int arow0 = lane >> 5;                          // 0/1 within call
  const int ac    = ((lane & 31) ^ (4 * wave)) << 2;    // swizzled f32 col
  const float* abase = A + (size_t)kstart * NN + j0 + ac;

  uint4 ybuf;
  auto issue = [&](int buf, int it){
    const float* at = abase + (size_t)(it * KT) * NN;
    float* ldsb = &Af[buf * ATILE];
#pragma unroll
    for (int p = 0; p < 4; p++){
      const int k0 = wave * 8 + p * 2;
      glds16(at + (size_t)(k0 + arow0) * NN, ldsb + k0 * BN);
    }
    ybuf = *(const uint4*)(yp + (size_t)it * KT);
  };
  auto stageY = [&](int buf){
    *(uint4*)(&Ylds[buf * YSZ + m * YPITCH + cY * 8]) = ybuf;
  };

  f32x4 acc[4][2];
#pragma unroll
  for (int a = 0; a < 4; a++)
#pragma unroll
    for (int b = 0; b < 2; b++)
      acc[a][b] = (f32x4){0.f, 0.f, 0.f, 0.f};

  issue(0, 0);
  stageY(0);
  __syncthreads();               // drains vmcnt(0): DMA + y in place

  for (int it = 0; it < NIT; ++it){
    if (it + 1 < NIT) issue((it + 1) & 1, it + 1);   // DMA into other buffer:
    // safe -- all waves passed barrier(it-1), so reads of that buffer are done.
    const unsigned short* Ab = (const unsigned short*)&Af[(it & 1) * ATILE];
    const short* Yb = &Ylds[(it & 1) * YSZ];

    short8 af[4];
#pragma unroll
    for (int mt = 0; mt < 4; mt++)    // A-frag: yT[m=16mt+nn][k=q*8..q*8+7]
      af[mt] = *(const short8*)(&Yb[(mt*16 + nn) * YPITCH + q*8]);
#pragma unroll
    for (int nt = 0; nt < 2; nt++){
      const int col = wave * 32 + nt * 16 + nn;
      // B-frag: hi-ushort of f32 at row k=q*8+jj, swizzled chunk (col>>2)^(4q)
      const unsigned short* bp =
          Ab + (q*8) * 256 + (((col >> 2) ^ (4*q)) * 8) + (col & 3) * 2 + 1;
      short8 bf;
#pragma unroll
      for (int jj = 0; jj < 8; jj++) bf[jj] = (short)bp[jj * 256];
#pragma unroll
      for (int mt = 0; mt < 4; mt++)
        acc[mt][nt] = __builtin_amdgcn_mfma_f32_16x16x32_bf16(af[mt], bf, acc[mt][nt], 0, 0, 0);
    }

    if (it + 1 < NIT){
      stageY((it + 1) & 1);   // ds_write after compute; barrier covers it
      __syncthreads();
    }
  }

  // epilogue: C/D layout col=lane&15, row=q*4+reg; bf16 RNE stores (L2 merges)
  unsigned short* pp = partb + (size_t)blockIdx.y * DD * NN;
#pragma unroll
  for (int mt = 0; mt < 4; mt++)
#pragma unroll
    for (int nt = 0; nt < 2; nt++)
#pragma unroll
      for (int v = 0; v < 4; v++){
        const int d   = mt * 16 + q * 4 + v;
        const int col = j0 + wave * 32 + nt * 16 + nn;
        pp[(size_t)d * NN + col] = f2bf(acc[mt][nt][v]);
      }
}

// ---------------------------------------------------------------------------
// Kernel 3: out[j][d] = accT[d][j] + sum_kb bf16(part[kb][d][j])
// 64-col stripes x 32-d halves; ushort2 part loads (full 64B sectors);
// 32x65 LDS transpose, both phases <=2-way banks.
// ---------------------------------------------------------------------------
__global__ __launch_bounds__(256) void k_out(
    const float* __restrict__ accT, const unsigned short* __restrict__ partb,
    float* __restrict__ out)
{
  __shared__ float t[32][65];
  const int tid = threadIdx.x;
  const int jb  = blockIdx.x * 64;
  const int dh  = blockIdx.y * 32;

#pragma unroll
  for (int rep = 0; rep < 4; rep++){
    const int dl = rep * 8 + (tid >> 5);
    const int j2 = (tid & 31) * 2;
    const size_t base = (size_t)(dh + dl) * NN + jb + j2;
    const float2 a2 = *(const float2*)(accT + base);
    float sx = a2.x, sy = a2.y;
#pragma unroll
    for (int kb = 0; kb < KSPLIT; kb++){
      const unsigned v = __builtin_nontemporal_load(
          (const unsigned*)(partb + (size_t)kb * DD * NN + base));
      sx += __uint_as_float((v & 0xFFFFu) << 16);
      sy += __uint_as_float(v & 0xFFFF0000u);
    }
    t[dl][j2] = sx; t[dl][j2 + 1] = sy;
  }
  __syncthreads();
#pragma unroll
  for (int pass = 0; pass < 8; pass++){
    const int j  = pass * 8 + (tid >> 5);
    const int dl = tid & 31;
    out[(size_t)(jb + j) * DD + dh + dl] = t[dl][j];
  }
}

extern "C" void kernel_launch(void* const* d_in, const int* in_sizes, int n_in,
                              void* d_out, int out_size, void* d_ws, size_t ws_size,
                              hipStream_t stream) {
  const float* x     = (const float*)d_in[0];
  const float* r     = (const float*)d_in[1];
  const float* A     = (const float*)d_in[2];
  const float* Wobj  = (const float*)d_in[3];
  const float* bobj  = (const float*)d_in[4];
  const float* Wnobj = (const float*)d_in[5];
  const float* bnobj = (const float*)d_in[6];
  const float* Wrel  = (const float*)d_in[7];
  const float* brel  = (const float*)d_in[8];
  const float* Wskip = (const float*)d_in[9];
  const float* bskip = (const float*)d_in[10];
  // d_in[11]/d_in[12] (Wa_w/Wa_b) provably unused: softmax rows sum to 1.

  char* ws = (char*)d_ws;
  float* accT         = (float*)ws;                                  // 2 MB
  unsigned short* yT  = (unsigned short*)(ws + (size_t)DD*NN*4);     // 1 MB
  unsigned short* pb  = (unsigned short*)(ws + 3u*1024*1024);        // 8 MB

  k_proj<<<dim3(32, 8), 256, 0, stream>>>(x, r, Wobj, bobj, Wnobj, bnobj,
                                          Wrel, brel, Wskip, bskip, accT, yT);
  k_spmm<<<dim3(NN / BN, KSPLIT), 256, 0, stream>>>(A, yT, pb);
  k_out<<<dim3(NN / 64, 2), 256, 0, stream>>>(accT, pb, (float*)d_out);
}

// Round 2
// 407.449 us; speedup vs baseline: 1.0048x; 1.0022x over previous
//
#include <hip/hip_runtime.h>

typedef __attribute__((ext_vector_type(8))) short short8;
typedef __attribute__((ext_vector_type(4))) float f32x4;

#define NN 8192
#define DD 64

// f32 -> bf16 RNE (y staging + part staging)
__device__ inline unsigned short f2bf(float f){
  unsigned b = __float_as_uint(f);
  b = (b + 0x7fffu + ((b >> 16) & 1u)) >> 16;
  return (unsigned short)b;
}

// async global->LDS, 16B per lane; LDS dest = uniform base + lane*16
__device__ __forceinline__ void glds16(const void* g, void* l){
  __builtin_amdgcn_global_load_lds((const __attribute__((address_space(1))) void*)g,
                                   (__attribute__((address_space(3))) void*)l, 16, 0, 0);
}

// ---------------------------------------------------------------------------
// Algebra (verified): softmax rows sum to 1 -> attn_agg == aggregated; Wa_*
// unused.  out = x@(Wobj+Wskip) + r@Wrel + A^T @ (x@Wnobj + bnobj) + biases
// A is exactly 0/1 -> f32 truncation to hi-ushort IS the exact bf16.
//
// R9: k_spmm rebuilt with depth-2 DMA pipeline: 3 LDS buffers, raw s_barrier,
// counted s_waitcnt vmcnt(5) (never 0 in steady state) -> A-tile DMAs get a
// full iteration of flight time instead of draining at every __syncthreads.
// k_proj reverted to grid-y=16 (2 blocks/CU; x/r re-reads are L2-resident).
// ---------------------------------------------------------------------------

// Kernel 1: accT[d][i] = x@(Wobj+Wskip)+r@Wrel+biases ; yT[d][i]=bf16(x@Wnobj+bnobj)
__global__ __launch_bounds__(256) void k_proj(
    const float* __restrict__ x, const float* __restrict__ r,
    const float* __restrict__ Wobj,  const float* __restrict__ bobj,
    const float* __restrict__ Wnobj, const float* __restrict__ bnobj,
    const float* __restrict__ Wrel,  const float* __restrict__ brel,
    const float* __restrict__ Wskip, const float* __restrict__ bskip,
    float* __restrict__ accT, unsigned short* __restrict__ yT)
{
  const int i  = blockIdx.x * 256 + threadIdx.x;   // row
  const int d0 = blockIdx.y * 4;                   // 4 output dims

  float ay[4] = {0.f,0.f,0.f,0.f}, az[4] = {0.f,0.f,0.f,0.f};
  const float4* xp = (const float4*)(x + (size_t)i * DD);
  const float4* rp = (const float4*)(r + (size_t)i * DD);

#pragma unroll
  for (int kb = 0; kb < 4; kb++){                  // 16 k per chunk
    float xv[16], rv[16];
#pragma unroll
    for (int p = 0; p < 4; p++){
      float4 u = xp[kb*4 + p];
      xv[4*p+0]=u.x; xv[4*p+1]=u.y; xv[4*p+2]=u.z; xv[4*p+3]=u.w;
      float4 v = rp[kb*4 + p];
      rv[4*p+0]=v.x; rv[4*p+1]=v.y; rv[4*p+2]=v.z; rv[4*p+3]=v.w;
    }
#pragma unroll
    for (int kk = 0; kk < 16; kk++){
      const int wb = (kb*16 + kk) * DD + d0;       // uniform -> s_loads
      const float xk = xv[kk], rk = rv[kk];
#pragma unroll
      for (int t = 0; t < 4; t++){
        ay[t] += xk * Wnobj[wb + t];
        az[t] += xk * Wobj [wb + t];
        az[t] += xk * Wskip[wb + t];
        az[t] += rk * Wrel [wb + t];
      }
    }
  }

#pragma unroll
  for (int t = 0; t < 4; t++){
    ay[t] += bnobj[d0 + t];
    az[t] += bobj[d0 + t] + brel[d0 + t] + bskip[d0 + t];
    yT[(size_t)(d0 + t) * NN + i]   = f2bf(ay[t]);   // coalesced
    accT[(size_t)(d0 + t) * NN + i] = az[t];
  }
}

// ---------------------------------------------------------------------------
// Kernel 2: partb[kb][d][j] = bf16( sum_{k in chunk} yT[d][k]*A[k][j] )
// BN=128, KSPLIT=8 -> 512 blocks = 2/CU. A staged RAW f32 by global_load_lds
// (source-XOR chunk swizzle); B-frag = hi-ushort of each f32 (exact bf16).
//
// Depth-2 pipeline, 3 buffers, per iteration:
//   issue(it+2): [y-load, 4 DMA]  (+5 VMEM)
//   vmcnt(5): tile it+1 fully landed (newest 5 = it+2's ops, program order
//             pinned by memory-clobber asm) -> stage y(it+1)
//   compute(it)  [tile it guaranteed by PREV iteration's barrier: every wave
//                 ran vmcnt(5) for tile it before that barrier]
//   lgkmcnt(0); s_barrier   <- NO vmcnt drain: it+2's DMAs fly across it
// Buffer hazards (mod-3): writes at iter it touch slots last read at iter
// it-1 (Af, before its barrier) / it-2 (Ylds) -> all barrier-separated.
// ---------------------------------------------------------------------------
#define BN 128
#define KSPLIT 8
#define KCH (NN / KSPLIT)    // 1024
#define KT 32                // k-depth per tile (one MFMA K)
#define NIT (KCH / KT)       // 32
#define ATILE (KT * BN)      // 4096 floats = 16 KB
#define YPITCH 40            // 32 + 8: af ds_read_b128 stays 2-way
#define YSZ (DD * YPITCH)    // 2560 shorts = 5 KB

__global__ __launch_bounds__(256) void k_spmm(
    const float* __restrict__ A,
    const unsigned short* __restrict__ yT,
    unsigned short* __restrict__ partb)
{
  __shared__ float Af[3 * ATILE];     // 48 KB
  __shared__ short Ylds[3 * YSZ];     // 15 KB

  const int tid  = threadIdx.x;
  const int lane = tid & 63;
  const int wave = tid >> 6;
  const int q    = lane >> 4;    // k-quad within fragment
  const int nn   = lane & 15;    // m (A-frag) / n (B-frag, C col) index

  const int j0     = blockIdx.x * BN;
  const int kstart = blockIdx.y * KCH;

  // y staging: 64 d-rows x 4 8-k chunks
  const int cY = tid & 3;
  const int m  = tid >> 2;       // 0..63
  const unsigned short* yp = yT + (size_t)m * NN + kstart + cY * 8;

  // A DMA: wave w, call p: rows k0=w*8+2p, k0+1 (512 B each = half-wave)
  const int arow0 = lane >> 5;                          // 0/1 within call
  const int ac    = ((lane & 31) ^ (4 * wave)) << 2;    // swizzled f32 col
  const float* abase = A + (size_t)kstart * NN + j0 + ac;

  auto issue = [&](int slot, int it) -> uint4 {
    uint4 y = *(const uint4*)(yp + (size_t)it * KT);
    const float* at = abase + (size_t)(it * KT) * NN;
    float* ldsb = &Af[slot * ATILE];
#pragma unroll
    for (int p = 0; p < 4; p++){
      const int k0 = wave * 8 + p * 2;
      glds16(at + (size_t)(k0 + arow0) * NN, ldsb + k0 * BN);
    }
    return y;
  };
  auto stageY = [&](int slot, uint4 v){
    *(uint4*)(&Ylds[slot * YSZ + m * YPITCH + cY * 8]) = v;
  };

  f32x4 acc[4][2];
#pragma unroll
  for (int a = 0; a < 4; a++)
#pragma unroll
    for (int b = 0; b < 2; b++)
      acc[a][b] = (f32x4){0.f, 0.f, 0.f, 0.f};

  // prologue: tiles 0 and 1 in flight; tile 0 landed + staged before loop
  uint4 ycur = issue(0, 0);
  asm volatile("" ::: "memory");                 // keep tile0 ops oldest
  uint4 ynxt = issue(1, 1);
  asm volatile("s_waitcnt vmcnt(5)" ::: "memory");   // tile0 landed
  stageY(0, ycur);
  ycur = ynxt;
  asm volatile("s_waitcnt lgkmcnt(0)" ::: "memory");
  __builtin_amdgcn_s_barrier();

  for (int it = 0; it < NIT; ++it){
    // issue tile it+2 (depth-2) and retire tile it+1
    if (it + 2 < NIT){
      ynxt = issue((it + 2) % 3, it + 2);
      asm volatile("s_waitcnt vmcnt(5)" ::: "memory");  // it+1 landed
      stageY((it + 1) % 3, ycur);
      ycur = ynxt;
    } else if (it + 1 < NIT){
      asm volatile("s_waitcnt vmcnt(0)" ::: "memory");  // last tile landed
      stageY((it + 1) % 3, ycur);
    }

    const unsigned short* Ab = (const unsigned short*)&Af[(it % 3) * ATILE];
    const short* Yb = &Ylds[(it % 3) * YSZ];

    short8 af[4];
#pragma unroll
    for (int mt = 0; mt < 4; mt++)    // A-frag: yT[m=16mt+nn][k=q*8..q*8+7]
      af[mt] = *(const short8*)(&Yb[(mt*16 + nn) * YPITCH + q*8]);
#pragma unroll
    for (int nt = 0; nt < 2; nt++){
      const int col = wave * 32 + nt * 16 + nn;
      // B-frag: hi-ushort of f32 at row k=q*8+jj, swizzled chunk (col>>2)^(4q)
      const unsigned short* bp =
          Ab + (q*8) * 256 + (((col >> 2) ^ (4*q)) * 8) + (col & 3) * 2 + 1;
      short8 bf;
#pragma unroll
      for (int jj = 0; jj < 8; jj++) bf[jj] = (short)bp[jj * 256];
#pragma unroll
      for (int mt = 0; mt < 4; mt++)
        acc[mt][nt] = __builtin_amdgcn_mfma_f32_16x16x32_bf16(af[mt], bf, acc[mt][nt], 0, 0, 0);
    }

    if (it + 1 < NIT){
      asm volatile("s_waitcnt lgkmcnt(0)" ::: "memory"); // stageY visible
      __builtin_amdgcn_s_barrier();     // NOTE: it+2's 5 VMEM stay in flight
    }
  }

  // epilogue: C/D layout col=lane&15, row=q*4+reg; bf16 RNE stores (L2/L3)
  unsigned short* pp = partb + (size_t)blockIdx.y * DD * NN;
#pragma unroll
  for (int mt = 0; mt < 4; mt++)
#pragma unroll
    for (int nt = 0; nt < 2; nt++)
#pragma unroll
      for (int v = 0; v < 4; v++){
        const int d   = mt * 16 + q * 4 + v;
        const int col = j0 + wave * 32 + nt * 16 + nn;
        pp[(size_t)d * NN + col] = f2bf(acc[mt][nt][v]);
      }
}

// ---------------------------------------------------------------------------
// Kernel 3: out[j][d] = accT[d][j] + sum_kb bf16(part[kb][d][j])
// 64-col stripes x 32-d halves; ushort2 part loads; 32x65 LDS transpose.
// ---------------------------------------------------------------------------
__global__ __launch_bounds__(256) void k_out(
    const float* __restrict__ accT, const unsigned short* __restrict__ partb,
    float* __restrict__ out)
{
  __shared__ float t[32][65];
  const int tid = threadIdx.x;
  const int jb  = blockIdx.x * 64;
  const int dh  = blockIdx.y * 32;

#pragma unroll
  for (int rep = 0; rep < 4; rep++){
    const int dl = rep * 8 + (tid >> 5);
    const int j2 = (tid & 31) * 2;
    const size_t base = (size_t)(dh + dl) * NN + jb + j2;
    const float2 a2 = *(const float2*)(accT + base);
    float sx = a2.x, sy = a2.y;
#pragma unroll
    for (int kb = 0; kb < KSPLIT; kb++){
      const unsigned v = __builtin_nontemporal_load(
          (const unsigned*)(partb + (size_t)kb * DD * NN + base));
      sx += __uint_as_float((v & 0xFFFFu) << 16);
      sy += __uint_as_float(v & 0xFFFF0000u);
    }
    t[dl][j2] = sx; t[dl][j2 + 1] = sy;
  }
  __syncthreads();
#pragma unroll
  for (int pass = 0; pass < 8; pass++){
    const int j  = pass * 8 + (tid >> 5);
    const int dl = tid & 31;
    out[(size_t)(jb + j) * DD + dh + dl] = t[dl][j];
  }
}

extern "C" void kernel_launch(void* const* d_in, const int* in_sizes, int n_in,
                              void* d_out, int out_size, void* d_ws, size_t ws_size,
                              hipStream_t stream) {
  const float* x     = (const float*)d_in[0];
  const float* r     = (const float*)d_in[1];
  const float* A     = (const float*)d_in[2];
  const float* Wobj  = (const float*)d_in[3];
  const float* bobj  = (const float*)d_in[4];
  const float* Wnobj = (const float*)d_in[5];
  const float* bnobj = (const float*)d_in[6];
  const float* Wrel  = (const float*)d_in[7];
  const float* brel  = (const float*)d_in[8];
  const float* Wskip = (const float*)d_in[9];
  const float* bskip = (const float*)d_in[10];
  // d_in[11]/d_in[12] (Wa_w/Wa_b) provably unused: softmax rows sum to 1.

  char* ws = (char*)d_ws;
  float* accT         = (float*)ws;                                  // 2 MB
  unsigned short* yT  = (unsigned short*)(ws + (size_t)DD*NN*4);     // 1 MB
  unsigned short* pb  = (unsigned short*)(ws + 3u*1024*1024);        // 8 MB

  k_proj<<<dim3(32, 16), 256, 0, stream>>>(x, r, Wobj, bobj, Wnobj, bnobj,
                                           Wrel, brel, Wskip, bskip, accT, yT);
  k_spmm<<<dim3(NN / BN, KSPLIT), 256, 0, stream>>>(A, yT, pb);
  k_out<<<dim3(NN / 64, 2), 256, 0, stream>>>(accT, pb, (float*)d_out);
}